// Round 8
// baseline (2910.102 us; speedup 1.0000x reference)
//
#include <hip/hip_runtime.h>
#include <cstddef>
#include <cstdint>

#define NG   100
#define NPG  1000
#define NN   (NG * NPG)       // 100000 nodes
#define NE   (NN * 16)        // 1600000 edges
#define EPG  (NE / NG)        // 16000 edges per graph (edges are graph-local)
#define FIN  64
#define HID  128
#define RD   64
#define SLOPE 0.01f
#define EPSV  1e-5f
#define NSTRIP 250            // nodes per GEMM/phi block (4 strips per graph)
#define SLICES 8              // feature slices per graph for spmm
#define SFEAT (HID / SLICES)  // 16 feats per slice
#define SDW   (SFEAT / 2)     // 8 dwords (bf16 pairs) per slice
#define ACCSTR 17             // padded fp32 stride per node (bank-conflict break)

using short8 = __attribute__((ext_vector_type(8))) short;   // 8 bf16 = 4 VGPRs
using f32x4  = __attribute__((ext_vector_type(4))) float;
typedef unsigned short u16;

__device__ __forceinline__ float leaky(float x) { return x >= 0.f ? x : SLOPE * x; }

// fp32 -> bf16 (round-to-nearest-even), bit pattern
__device__ __forceinline__ u16 f2bf(float f) {
  union { float f; unsigned u; } v; v.f = f;
  return (u16)((v.u + 0x7fffu + ((v.u >> 16) & 1u)) >> 16);
}
__device__ __forceinline__ float bf2f(u16 u) {
  union { unsigned u; float f; } v; v.u = ((unsigned)u) << 16;
  return v.f;
}

// XCD-affinity swizzle: block->XCD heuristic is blockIdx%8; pin graph g to
// XCD g%8 so producer/consumer blocks of one graph share an L2.
__device__ __forceinline__ bool swz(int b, int per_g, int& g, int& part) {
  const int xcd = b & 7;
  const int slot = b >> 3;
  g = xcd + 8 * (slot / per_g);
  part = slot % per_g;
  return g < NG;
}

// ---------------------------------------------------------------------------
// One-shot bf16 transpose of the four GEMM weight matrices: Wt[n][k]=W[k][n].
// ---------------------------------------------------------------------------
__global__ __launch_bounds__(256) void wt_k(const float* __restrict__ W1,
                                            const float* __restrict__ W2,
                                            const float* __restrict__ R1,
                                            const float* __restrict__ R2,
                                            u16* __restrict__ Wt1,
                                            u16* __restrict__ Wt2,
                                            u16* __restrict__ Rt1,
                                            u16* __restrict__ Rt2) {
  const int idx = blockIdx.x * 256 + threadIdx.x;  // 57344 total
  if (idx < FIN * HID) {
    const int n = idx >> 6, k = idx & 63;          // Wt1 [128][64]
    Wt1[idx] = f2bf(W1[k * HID + n]);
  } else {
    const int j = idx - FIN * HID;
    const int m = j >> 14, r = j & 16383;
    const int n = r >> 7, k = r & 127;
    const float* s = (m == 0) ? W2 : (m == 1) ? R1 : R2;
    u16* d = (m == 0) ? Wt2 : (m == 1) ? Rt1 : Rt2;
    d[r] = f2bf(s[k * HID + n]);
  }
}

// ---------------------------------------------------------------------------
// Degree counts (int): out over src, in over dst. Full-occupancy histogram.
// ---------------------------------------------------------------------------
__global__ __launch_bounds__(256) void degrees_k(const int* __restrict__ src,
                                                 const int* __restrict__ dst,
                                                 int* __restrict__ cout_,
                                                 int* __restrict__ cin_) {
  int e = blockIdx.x * 256 + threadIdx.x;
  if (e < NE) {
    atomicAdd(&cout_[src[e]], 1);
    atomicAdd(&cin_[dst[e]], 1);
  }
}

// ---------------------------------------------------------------------------
// LDS-scatter aggregation straight from the raw edge list (NO CSR/buckets):
// block = (graph g, feat-slice of 16). acc[1000][17] fp32 in LDS; stream the
// graph's 16000 edges (8 edges/wave, 8 lanes/edge, one bf16-pair dword each),
// ds_add_f32 accumulate. Epilogue: *in_isqrt, pack bf16 AGG, and DIRECT
// (atomic-free) per-(g,feat) stats stores — each feat owned by one block.
// ---------------------------------------------------------------------------
__global__ __launch_bounds__(512) void spmm_k(const u16* __restrict__ H,
                                              const int* __restrict__ src,
                                              const int* __restrict__ dst,
                                              const float* __restrict__ ew,
                                              const int* __restrict__ cin_,
                                              u16* __restrict__ AGG,
                                              float* __restrict__ sx,
                                              float* __restrict__ sq) {
  __shared__ float acc[NPG * ACCSTR];   // 68 KB
  __shared__ float redx[64][SFEAT];     //  4 KB
  __shared__ float redq[64][SFEAT];     //  4 KB
  int g, slice;
  if (!swz(blockIdx.x, SLICES, g, slice)) return;
  const int tid = threadIdx.x;
  const int nb = g * NPG;
  const int eb = g * EPG;
  const int fbase = slice * SFEAT;
  const int d = tid & (SDW - 1);        // dword index in slice (0..7), fixed/thread

  for (int i = tid; i < NPG * ACCSTR; i += 512) acc[i] = 0.f;
  __syncthreads();

  // main loop: 64 edges per block-iteration (512 threads / 8 lanes per edge)
  for (int e0 = tid >> 3; e0 < EPG; e0 += 64) {
    const int e = eb + e0;
    const int s = src[e];
    const int dn = dst[e] - nb;
    const float w = ew[e];
    const unsigned hv = *(const unsigned*)(H + (size_t)s * HID + fbase + d * 2);
    unsafeAtomicAdd(&acc[dn * ACCSTR + d * 2], __uint_as_float(hv << 16) * w);
    unsafeAtomicAdd(&acc[dn * ACCSTR + d * 2 + 1], __uint_as_float(hv & 0xffff0000u) * w);
  }
  __syncthreads();

  // epilogue: isq scale, bf16 pack, per-thread stats partials (fixed 2 feats)
  float sx0 = 0.f, sx1 = 0.f, sq0 = 0.f, sq1 = 0.f;
  for (int i = tid; i < NPG * SDW; i += 512) {
    const int node = i >> 3;  // i&7 == d (stride 512 preserves low bits)
    const float isq = rsqrtf(fmaxf((float)cin_[nb + node], 1.0f));
    const float x0 = acc[node * ACCSTR + d * 2] * isq;
    const float x1 = acc[node * ACCSTR + d * 2 + 1] * isq;
    const unsigned pk = (unsigned)f2bf(x0) | ((unsigned)f2bf(x1) << 16);
    *(unsigned*)(AGG + (size_t)(nb + node) * HID + fbase + d * 2) = pk;
    sx0 += x0; sx1 += x1; sq0 += x0 * x0; sq1 += x1 * x1;
  }
  redx[tid >> 3][d * 2] = sx0; redx[tid >> 3][d * 2 + 1] = sx1;
  redq[tid >> 3][d * 2] = sq0; redq[tid >> 3][d * 2 + 1] = sq1;
  __syncthreads();
  if (tid < SFEAT) {
    float s1 = 0.f, s2 = 0.f;
#pragma unroll 8
    for (int r = 0; r < 64; ++r) { s1 += redx[r][tid]; s2 += redq[r][tid]; }
    sx[g * HID + fbase + tid] = s1;   // direct store — block owns these feats
    sq[g * HID + fbase + tid] = s2;
  }
}

// ---------------------------------------------------------------------------
// Layer-1 GEMM (MFMA bf16), XCD-swizzled, 250-row strips, bf16 output.
// ---------------------------------------------------------------------------
__global__ __launch_bounds__(256) void gemm1_k(const float* __restrict__ X,
                                               const u16* __restrict__ Wt,
                                               const int* __restrict__ cout_,
                                               u16* __restrict__ Y) {
  __shared__ u16 Xl[64 * FIN];
  __shared__ u16 Wl[HID * FIN];
  const int tid = threadIdx.x;
  const int wave = tid >> 6, lane = tid & 63, l15 = lane & 15, quad = lane >> 4;
  int g, part;
  if (!swz(blockIdx.x, 4, g, part)) return;
  const int base = g * NPG + part * NSTRIP;

  for (int i = tid; i < HID * (FIN / 8); i += 256) {  // 1024 chunks
    const int n = i >> 3, c = i & 7;
    const short8 w = *(const short8*)(Wt + n * FIN + c * 8);
    *(short8*)&Wl[n * FIN + ((c ^ (n & 7)) << 3)] = w;
  }
  for (int pass = 0; pass < 4; ++pass) {
    __syncthreads();
    for (int i = tid; i < 64 * (FIN / 4); i += 256) {  // 1024
      const int r = i >> 4;
      const int kq = i & 15;
      const int rowi = pass * 64 + r;
      ushort4 u = make_ushort4(0, 0, 0, 0);
      if (rowi < NSTRIP) {
        const float4 x = *(const float4*)(X + (size_t)(base + rowi) * FIN + kq * 4);
        u.x = f2bf(x.x); u.y = f2bf(x.y); u.z = f2bf(x.z); u.w = f2bf(x.w);
      }
      const int c = kq >> 1, half = kq & 1;
      *(ushort4*)&Xl[r * FIN + (((c ^ (r & 7)) << 3) | (half << 2))] = u;
    }
    __syncthreads();
    short8 a[2];
    const int arow = wave * 16 + l15;
#pragma unroll
    for (int kt = 0; kt < 2; ++kt)
      a[kt] = *(const short8*)&Xl[arow * FIN + (((kt * 4 + quad) ^ (l15 & 7)) << 3)];
    float sc[4];
    int rows[4];
#pragma unroll
    for (int r = 0; r < 4; ++r) {
      rows[r] = pass * 64 + wave * 16 + quad * 4 + r;
      sc[r] = (rows[r] < NSTRIP) ? rsqrtf(fmaxf((float)cout_[base + rows[r]], 1.0f)) : 0.f;
    }
#pragma unroll
    for (int ct = 0; ct < 8; ++ct) {
      f32x4 acc = {0.f, 0.f, 0.f, 0.f};
      const int brow = ct * 16 + l15;
#pragma unroll
      for (int kt = 0; kt < 2; ++kt) {
        const short8 b = *(const short8*)&Wl[brow * FIN + (((kt * 4 + quad) ^ (l15 & 7)) << 3)];
        acc = __builtin_amdgcn_mfma_f32_16x16x32_bf16(a[kt], b, acc, 0, 0, 0);
      }
      const int n = ct * 16 + l15;
#pragma unroll
      for (int r = 0; r < 4; ++r)
        if (rows[r] < NSTRIP) Y[(size_t)(base + rows[r]) * HID + n] = f2bf(acc[r] * sc[r]);
    }
  }
}

// ---------------------------------------------------------------------------
// Layer-2 GEMM (MFMA bf16), fused GraphNorm apply, bf16 in/out, XCD-swizzled.
// ---------------------------------------------------------------------------
__global__ __launch_bounds__(256) void gemm_norm_k(const u16* __restrict__ Xb,
                                                   const u16* __restrict__ Wt,
                                                   const float* __restrict__ An,
                                                   const float* __restrict__ Bn,
                                                   const int* __restrict__ cout_,
                                                   u16* __restrict__ Y) {
  __shared__ u16 Xl[64 * HID];
  __shared__ u16 Wl[HID * HID];
  const int tid = threadIdx.x;
  const int wave = tid >> 6, lane = tid & 63, l15 = lane & 15, quad = lane >> 4;
  int g, part;
  if (!swz(blockIdx.x, 4, g, part)) return;
  const int base = g * NPG + part * NSTRIP;

  for (int i = tid; i < HID * (HID / 8); i += 256) {  // 2048 chunks
    const int n = i >> 4, c = i & 15;
    const short8 w = *(const short8*)(Wt + n * HID + c * 8);
    *(short8*)&Wl[n * HID + ((c ^ (n & 15)) << 3)] = w;
  }
  for (int pass = 0; pass < 4; ++pass) {
    __syncthreads();
    for (int i = tid; i < 64 * 16; i += 256) {  // 4 iters, 8 elems each
      const int r = i >> 4;
      const int c8 = i & 15;
      const int rowi = pass * 64 + r;
      short8 o = {0, 0, 0, 0, 0, 0, 0, 0};
      if (rowi < NSTRIP) {
        const int node = base + rowi;
        const short8 xs = *(const short8*)(Xb + (size_t)node * HID + c8 * 8);
        const float4 Aa = *(const float4*)(An + (size_t)g * HID + c8 * 8);
        const float4 Ab = *(const float4*)(An + (size_t)g * HID + c8 * 8 + 4);
        const float4 Ba = *(const float4*)(Bn + (size_t)g * HID + c8 * 8);
        const float4 Bb = *(const float4*)(Bn + (size_t)g * HID + c8 * 8 + 4);
        const float Av[8] = {Aa.x, Aa.y, Aa.z, Aa.w, Ab.x, Ab.y, Ab.z, Ab.w};
        const float Bv[8] = {Ba.x, Ba.y, Ba.z, Ba.w, Bb.x, Bb.y, Bb.z, Bb.w};
#pragma unroll
        for (int j = 0; j < 8; ++j)
          o[j] = (short)f2bf(leaky(fmaf(Av[j], bf2f((u16)xs[j]), Bv[j])));
      }
      *(short8*)&Xl[r * HID + ((c8 ^ (r & 15)) << 3)] = o;
    }
    __syncthreads();
    short8 a[4];
    const int arow = wave * 16 + l15;
#pragma unroll
    for (int kt = 0; kt < 4; ++kt)
      a[kt] = *(const short8*)&Xl[arow * HID + (((kt * 4 + quad) ^ l15) << 3)];
    float sc[4];
    int rows[4];
#pragma unroll
    for (int r = 0; r < 4; ++r) {
      rows[r] = pass * 64 + wave * 16 + quad * 4 + r;
      sc[r] = (rows[r] < NSTRIP) ? rsqrtf(fmaxf((float)cout_[base + rows[r]], 1.0f)) : 0.f;
    }
#pragma unroll
    for (int ct = 0; ct < 8; ++ct) {
      f32x4 acc = {0.f, 0.f, 0.f, 0.f};
      const int brow = ct * 16 + l15;
#pragma unroll
      for (int kt = 0; kt < 4; ++kt) {
        const short8 b = *(const short8*)&Wl[brow * HID + (((kt * 4 + quad) ^ l15) << 3)];
        acc = __builtin_amdgcn_mfma_f32_16x16x32_bf16(a[kt], b, acc, 0, 0, 0);
      }
      const int n = ct * 16 + l15;
#pragma unroll
      for (int r = 0; r < 4; ++r)
        if (rows[r] < NSTRIP) Y[(size_t)(base + rows[r]) * HID + n] = f2bf(acc[r] * sc[r]);
    }
  }
}

// ---------------------------------------------------------------------------
// Readout phi+pool (MFMA bf16), fused norm apply, bf16 input, XCD-swizzled.
// ---------------------------------------------------------------------------
__global__ __launch_bounds__(256) void phi_pool_k(const u16* __restrict__ Xb,
                                                  const float* __restrict__ An,
                                                  const float* __restrict__ Bn,
                                                  const u16* __restrict__ Wt,
                                                  const float* __restrict__ b1,
                                                  float* __restrict__ phi_sum,
                                                  float* __restrict__ h_sum) {
  __shared__ u16 Xl[64 * HID];          // 16 KB
  __shared__ u16 Wl[HID * HID];         // 32 KB
  __shared__ float red[16][HID];        //  8 KB
  __shared__ float hred[16][HID];       //  8 KB  (64 KB total)
  const int tid = threadIdx.x;
  const int wave = tid >> 6, lane = tid & 63, l15 = lane & 15, quad = lane >> 4;
  int g, part;
  if (!swz(blockIdx.x, 4, g, part)) return;
  const int base = g * NPG + part * NSTRIP;

  for (int i = tid; i < HID * (HID / 8); i += 256) {
    const int n = i >> 4, c = i & 15;
    const short8 w = *(const short8*)(Wt + n * HID + c * 8);
    *(short8*)&Wl[n * HID + ((c ^ (n & 15)) << 3)] = w;
  }
  float bcol[8];
#pragma unroll
  for (int ct = 0; ct < 8; ++ct) bcol[ct] = b1[ct * 16 + l15];

  float pooled[8] = {0.f, 0.f, 0.f, 0.f, 0.f, 0.f, 0.f, 0.f};
  float hp[8] = {0.f, 0.f, 0.f, 0.f, 0.f, 0.f, 0.f, 0.f};

  for (int pass = 0; pass < 4; ++pass) {
    __syncthreads();
    for (int i = tid; i < 64 * 16; i += 256) {
      const int r = i >> 4;
      const int c8 = i & 15;   // == tid&15 (stride 256)
      const int rowi = pass * 64 + r;
      short8 o = {0, 0, 0, 0, 0, 0, 0, 0};
      if (rowi < NSTRIP) {
        const int node = base + rowi;
        const short8 xs = *(const short8*)(Xb + (size_t)node * HID + c8 * 8);
        const float4 Aa = *(const float4*)(An + (size_t)g * HID + c8 * 8);
        const float4 Ab = *(const float4*)(An + (size_t)g * HID + c8 * 8 + 4);
        const float4 Ba = *(const float4*)(Bn + (size_t)g * HID + c8 * 8);
        const float4 Bb = *(const float4*)(Bn + (size_t)g * HID + c8 * 8 + 4);
        const float Av[8] = {Aa.x, Aa.y, Aa.z, Aa.w, Ab.x, Ab.y, Ab.z, Ab.w};
        const float Bv[8] = {Ba.x, Ba.y, Ba.z, Ba.w, Bb.x, Bb.y, Bb.z, Bb.w};
#pragma unroll
        for (int j = 0; j < 8; ++j) {
          const float xn = leaky(fmaf(Av[j], bf2f((u16)xs[j]), Bv[j]));
          hp[j] += xn;
          o[j] = (short)f2bf(xn);
        }
      }
      *(short8*)&Xl[r * HID + ((c8 ^ (r & 15)) << 3)] = o;
    }
    __syncthreads();
    short8 a[4];
    const int arow = wave * 16 + l15;
#pragma unroll
    for (int kt = 0; kt < 4; ++kt)
      a[kt] = *(const short8*)&Xl[arow * HID + (((kt * 4 + quad) ^ l15) << 3)];
#pragma unroll
    for (int ct = 0; ct < 8; ++ct) {
      f32x4 acc = {0.f, 0.f, 0.f, 0.f};
      const int brow = ct * 16 + l15;
#pragma unroll
      for (int kt = 0; kt < 4; ++kt) {
        const short8 b = *(const short8*)&Wl[brow * HID + (((kt * 4 + quad) ^ l15) << 3)];
        acc = __builtin_amdgcn_mfma_f32_16x16x32_bf16(a[kt], b, acc, 0, 0, 0);
      }
#pragma unroll
      for (int r = 0; r < 4; ++r) {
        const int rowi = pass * 64 + wave * 16 + quad * 4 + r;
        if (rowi < NSTRIP) pooled[ct] += leaky(acc[r] + bcol[ct]);
      }
    }
  }
  const int qi = wave * 4 + quad;
#pragma unroll
  for (int ct = 0; ct < 8; ++ct) red[qi][ct * 16 + l15] = pooled[ct];
#pragma unroll
  for (int j = 0; j < 8; ++j) hred[tid >> 4][(tid & 15) * 8 + j] = hp[j];
  __syncthreads();
  if (tid < HID) {
    float s = 0.f;
#pragma unroll
    for (int q = 0; q < 16; ++q) s += red[q][tid];
    unsafeAtomicAdd(&phi_sum[g * HID + tid], s);
  } else {
    const int t = tid - HID;
    float s = 0.f;
#pragma unroll
    for (int rr = 0; rr < 16; ++rr) s += hred[rr][t];
    unsafeAtomicAdd(&h_sum[g * HID + t], s);
  }
}

// ---------------------------------------------------------------------------
// Fold stats into affine: normalized = A*x + B per (graph, feat).
// ---------------------------------------------------------------------------
__global__ __launch_bounds__(HID) void stats_k(const float* __restrict__ sx,
                                               const float* __restrict__ sq,
                                               const float* __restrict__ alpha,
                                               const float* __restrict__ gamma,
                                               const float* __restrict__ beta,
                                               float* __restrict__ An,
                                               float* __restrict__ Bn) {
  const int g = (blockIdx.x & 7) + 8 * (blockIdx.x >> 3);
  if (g >= NG) return;
  const int j = threadIdx.x;
  const float mean = sx[g * HID + j] * (1.0f / NPG);
  const float ex2 = sq[g * HID + j] * (1.0f / NPG);
  const float am = alpha[j] * mean;
  float var = ex2 - 2.0f * am * mean + am * am;
  var = fmaxf(var, 0.0f);
  const float rstd = rsqrtf(var + EPSV);
  const float A = gamma[j] * rstd;
  An[g * HID + j] = A;
  Bn[g * HID + j] = beta[j] - A * am;
}

// ---------------------------------------------------------------------------
// Readout part 2.
// ---------------------------------------------------------------------------
__global__ __launch_bounds__(64) void finalize_k(const float* __restrict__ phi_sum,
                                                 const float* __restrict__ h_sum,
                                                 const float* __restrict__ w2,
                                                 const float* __restrict__ b2,
                                                 float* __restrict__ out,
                                                 int roff, int moff) {
  const int g = blockIdx.x;
  const int j = threadIdx.x;  // 0..63
  float acc = b2[j];
#pragma unroll 8
  for (int k = 0; k < HID; ++k)
    acc += (phi_sum[g * HID + k] * (1.0f / NPG)) * w2[k * RD + j];
  const float r = leaky(acc);
  out[g * 384 + roff + j] = leaky(r);
  out[g * 384 + moff + j] = leaky(h_sum[g * HID + j] * (1.0f / NPG));
  out[g * 384 + moff + 64 + j] = leaky(h_sum[g * HID + 64 + j] * (1.0f / NPG));
}

// ---------------------------------------------------------------------------
extern "C" void kernel_launch(void* const* d_in, const int* in_sizes, int n_in,
                              void* d_out, int out_size, void* d_ws, size_t ws_size,
                              hipStream_t stream) {
  const float* node_feats = (const float*)d_in[0];
  const float* ew   = (const float*)d_in[1];
  const float* W1   = (const float*)d_in[2];
  const float* W2   = (const float*)d_in[3];
  const float* g1a  = (const float*)d_in[4];
  const float* g1g  = (const float*)d_in[5];
  const float* g1b  = (const float*)d_in[6];
  const float* g2a  = (const float*)d_in[7];
  const float* g2g  = (const float*)d_in[8];
  const float* g2b  = (const float*)d_in[9];
  const float* r1w1 = (const float*)d_in[10];
  const float* r1b1 = (const float*)d_in[11];
  const float* r1w2 = (const float*)d_in[12];
  const float* r1b2 = (const float*)d_in[13];
  const float* r2w1 = (const float*)d_in[14];
  const float* r2b1 = (const float*)d_in[15];
  const float* r2w2 = (const float*)d_in[16];
  const float* r2b2 = (const float*)d_in[17];
  const int* src = (const int*)d_in[18];
  const int* dst = (const int*)d_in[19];
  float* out = (float*)d_out;

  // workspace layout (zeroed region first: phi/h pooled sums + cin/cout)
  char* wsb = (char*)d_ws;
  float* ps1     = (float*)wsb;                       // NG*HID x4, zeroed
  float* hs1     = ps1 + NG * HID;
  float* ps2     = hs1 + NG * HID;
  float* hs2     = ps2 + NG * HID;
  int*   cin     = (int*)(hs2 + NG * HID);            // NN  } zeroed
  int*   cout_   = cin + NN;                          // NN  }
  float* sx1     = (float*)(cout_ + NN);              // NG*HID x4 (direct-store)
  float* sq1     = sx1 + NG * HID;
  float* sx2     = sq1 + NG * HID;
  float* sq2     = sx2 + NG * HID;
  float* A1      = sq2 + NG * HID;                    // NG*HID x4
  float* B1      = A1 + NG * HID;
  float* A2      = B1 + NG * HID;
  float* B2      = A2 + NG * HID;
  u16*   Wt1     = (u16*)(B2 + NG * HID);             // 128*64
  u16*   Wt2     = Wt1 + HID * FIN;                   // 128*128 x3
  u16*   Rt1     = Wt2 + HID * HID;
  u16*   Rt2     = Rt1 + HID * HID;
  u16*   bufA    = Rt2 + HID * HID;                   // NN*HID bf16
  u16*   bufB    = bufA + (size_t)NN * HID;           // NN*HID bf16

  const size_t zero_bytes = (size_t)(4 * NG * HID) * sizeof(float) +
                            (size_t)(2 * NN) * sizeof(int);
  hipMemsetAsync(d_ws, 0, zero_bytes, stream);

  // weight transpose + degree histograms (per call)
  wt_k<<<(FIN * HID + 3 * HID * HID) / 256, 256, 0, stream>>>(
      W1, W2, r1w1, r2w1, Wt1, Wt2, Rt1, Rt2);
  degrees_k<<<(NE + 255) / 256, 256, 0, stream>>>(src, dst, cout_, cin);

  const int gemm_grid = 8 * 4 * 13;       // XCD-swizzled, 4 strips/graph
  const int spmm_grid = 8 * SLICES * 13;  // XCD-swizzled, 8 slices/graph
  const int stats_grid = 8 * 13;

  // ---- layer 1 ----
  gemm1_k<<<gemm_grid, 256, 0, stream>>>(node_feats, Wt1, cout_, bufA);
  spmm_k<<<spmm_grid, 512, 0, stream>>>(bufA, src, dst, ew, cin, bufB, sx1, sq1);
  stats_k<<<stats_grid, HID, 0, stream>>>(sx1, sq1, g1a, g1g, g1b, A1, B1);
  phi_pool_k<<<gemm_grid, 256, 0, stream>>>(bufB, A1, B1, Rt1, r1b1, ps1, hs1);
  finalize_k<<<NG, 64, 0, stream>>>(ps1, hs1, r1w2, r1b2, out, 0, 64);

  // ---- layer 2 ----
  gemm_norm_k<<<gemm_grid, 256, 0, stream>>>(bufB, Wt2, A1, B1, cout_, bufA);
  spmm_k<<<spmm_grid, 512, 0, stream>>>(bufA, src, dst, ew, cin, bufB, sx2, sq2);
  stats_k<<<stats_grid, HID, 0, stream>>>(sx2, sq2, g2a, g2g, g2b, A2, B2);
  phi_pool_k<<<gemm_grid, 256, 0, stream>>>(bufB, A2, B2, Rt2, r2b1, ps2, hs2);
  finalize_k<<<NG, 64, 0, stream>>>(ps2, hs2, r2w2, r2b2, out, 192, 256);
}

// Round 9
// 361.446 us; speedup vs baseline: 8.0513x; 8.0513x over previous
//
#include <hip/hip_runtime.h>
#include <cstddef>
#include <cstdint>

#define NG   100
#define NPG  1000
#define NN   (NG * NPG)       // 100000 nodes
#define NE   (NN * 16)        // 1600000 edges
#define EPG  (NE / NG)        // 16000 edges per graph (edges are graph-local)
#define FIN  64
#define HID  128
#define RD   64
#define SLOPE 0.01f
#define EPSV  1e-5f
#define NSTRIP 250            // nodes per GEMM/phi block (4 strips per graph)
#define GSN   40              // nodes per gather block (25 strips per graph)

using short8 = __attribute__((ext_vector_type(8))) short;   // 8 bf16 = 4 VGPRs
using f32x4  = __attribute__((ext_vector_type(4))) float;
typedef unsigned short u16;

__device__ __forceinline__ float leaky(float x) { return x >= 0.f ? x : SLOPE * x; }

// fp32 -> bf16 (round-to-nearest-even), bit pattern
__device__ __forceinline__ u16 f2bf(float f) {
  union { float f; unsigned u; } v; v.f = f;
  return (u16)((v.u + 0x7fffu + ((v.u >> 16) & 1u)) >> 16);
}
__device__ __forceinline__ float bf2f(u16 u) {
  union { unsigned u; float f; } v; v.u = ((unsigned)u) << 16;
  return v.f;
}

// XCD-affinity swizzle: block->XCD heuristic is blockIdx%8; pin graph g to
// XCD g%8 so producer/consumer blocks of one graph share an L2.
__device__ __forceinline__ bool swz(int b, int per_g, int& g, int& part) {
  const int xcd = b & 7;
  const int slot = b >> 3;
  g = xcd + 8 * (slot / per_g);
  part = slot % per_g;
  return g < NG;
}

// ---------------------------------------------------------------------------
// One-shot bf16 transpose of the four GEMM weight matrices: Wt[n][k]=W[k][n].
// ---------------------------------------------------------------------------
__global__ __launch_bounds__(256) void wt_k(const float* __restrict__ W1,
                                            const float* __restrict__ W2,
                                            const float* __restrict__ R1,
                                            const float* __restrict__ R2,
                                            u16* __restrict__ Wt1,
                                            u16* __restrict__ Wt2,
                                            u16* __restrict__ Rt1,
                                            u16* __restrict__ Rt2) {
  const int idx = blockIdx.x * 256 + threadIdx.x;  // 57344 total
  if (idx < FIN * HID) {
    const int n = idx >> 6, k = idx & 63;          // Wt1 [128][64]
    Wt1[idx] = f2bf(W1[k * HID + n]);
  } else {
    const int j = idx - FIN * HID;
    const int m = j >> 14, r = j & 16383;
    const int n = r >> 7, k = r & 127;
    const float* s = (m == 0) ? W2 : (m == 1) ? R1 : R2;
    u16* d = (m == 0) ? Wt2 : (m == 1) ? Rt1 : Rt2;
    d[r] = f2bf(s[k * HID + n]);
  }
}

// ---------------------------------------------------------------------------
// Per-graph CSR build (LDS histogram + shuffle-scan + LDS cursors), one
// 1024-thread block per graph, XCD-swizzled to g%8. CSR record = int2
// {src, bitcast(w)} -> single 8B store. Direct cin/cout stores (no memset).
// ---------------------------------------------------------------------------
__global__ __launch_bounds__(1024) void build_k(const int* __restrict__ src,
                                                const int* __restrict__ dst,
                                                const float* __restrict__ ew,
                                                int* __restrict__ cin_,
                                                int* __restrict__ cout_,
                                                int* __restrict__ offs,
                                                int2* __restrict__ csr) {
  __shared__ int hin[NPG];
  __shared__ int hout[NPG];
  __shared__ int cur[NPG];
  __shared__ int wtot[16];
  int g, part;
  if (!swz(blockIdx.x, 1, g, part)) return;   // grid 8*13 = 104, 4 idle
  const int t = threadIdx.x;
  const int lane = t & 63, wave = t >> 6;
  const int nb = g * NPG, eb = g * EPG;
  if (t < NPG) { hin[t] = 0; hout[t] = 0; }
  __syncthreads();
  for (int e = t; e < EPG; e += 1024) {
    atomicAdd(&hout[src[eb + e] - nb], 1);
    atomicAdd(&hin[dst[eb + e] - nb], 1);
  }
  __syncthreads();
  int v[4];
  int loc = 0;
#pragma unroll
  for (int k = 0; k < 4; ++k) {
    const int idx = t * 4 + k;
    v[k] = (idx < NPG) ? hin[idx] : 0;
    loc += v[k];
  }
  // intra-wave inclusive scan of loc (6 shuffle steps, no barriers)
  int incl = loc;
#pragma unroll
  for (int d = 1; d < 64; d <<= 1) {
    const int x = __shfl_up(incl, d);
    if (lane >= d) incl += x;
  }
  if (lane == 63) wtot[wave] = incl;
  if (t < NPG) { cin_[nb + t] = hin[t]; cout_[nb + t] = hout[t]; }
  __syncthreads();
  int wexc = 0;
  for (int i = 0; i < wave; ++i) wexc += wtot[i];   // broadcast LDS reads
  int run = eb + wexc + (incl - loc);               // exclusive prefix
#pragma unroll
  for (int k = 0; k < 4; ++k) {
    const int idx = t * 4 + k;
    if (idx < NPG) {
      offs[nb + idx] = run;
      cur[idx] = run;
      run += v[k];
    }
  }
  __syncthreads();
  for (int e = t; e < EPG; e += 1024) {
    const int d = dst[eb + e] - nb;
    const int pos = atomicAdd(&cur[d], 1);
    int2 rec;
    rec.x = src[eb + e];
    rec.y = __float_as_int(ew[eb + e]);
    csr[pos] = rec;
  }
}

// ---------------------------------------------------------------------------
// Layer-1 GEMM (MFMA bf16), XCD-swizzled, 250-row strips, bf16 output.
// LDS: unpadded rows, 8-bf16 chunks XOR-swizzled by (row & mask).
// A-frag A[m=lane&15][k=quad*8+j]; B-frag B[k=quad*8+j][n=lane&15];
// C/D col=lane&15, row=quad*4+reg (m89-verified).
// ---------------------------------------------------------------------------
__global__ __launch_bounds__(256) void gemm1_k(const float* __restrict__ X,
                                               const u16* __restrict__ Wt,
                                               const int* __restrict__ cout_,
                                               u16* __restrict__ Y) {
  __shared__ u16 Xl[64 * FIN];
  __shared__ u16 Wl[HID * FIN];
  const int tid = threadIdx.x;
  const int wave = tid >> 6, lane = tid & 63, l15 = lane & 15, quad = lane >> 4;
  int g, part;
  if (!swz(blockIdx.x, 4, g, part)) return;
  const int base = g * NPG + part * NSTRIP;

  for (int i = tid; i < HID * (FIN / 8); i += 256) {  // 1024 chunks
    const int n = i >> 3, c = i & 7;
    const short8 w = *(const short8*)(Wt + n * FIN + c * 8);
    *(short8*)&Wl[n * FIN + ((c ^ (n & 7)) << 3)] = w;
  }
  for (int pass = 0; pass < 4; ++pass) {
    __syncthreads();
    for (int i = tid; i < 64 * (FIN / 4); i += 256) {  // 1024
      const int r = i >> 4;
      const int kq = i & 15;
      const int rowi = pass * 64 + r;
      ushort4 u = make_ushort4(0, 0, 0, 0);
      if (rowi < NSTRIP) {
        const float4 x = *(const float4*)(X + (size_t)(base + rowi) * FIN + kq * 4);
        u.x = f2bf(x.x); u.y = f2bf(x.y); u.z = f2bf(x.z); u.w = f2bf(x.w);
      }
      const int c = kq >> 1, half = kq & 1;
      *(ushort4*)&Xl[r * FIN + (((c ^ (r & 7)) << 3) | (half << 2))] = u;
    }
    __syncthreads();
    short8 a[2];
    const int arow = wave * 16 + l15;
#pragma unroll
    for (int kt = 0; kt < 2; ++kt)
      a[kt] = *(const short8*)&Xl[arow * FIN + (((kt * 4 + quad) ^ (l15 & 7)) << 3)];
    float sc[4];
    int rows[4];
#pragma unroll
    for (int r = 0; r < 4; ++r) {
      rows[r] = pass * 64 + wave * 16 + quad * 4 + r;
      sc[r] = (rows[r] < NSTRIP) ? rsqrtf(fmaxf((float)cout_[base + rows[r]], 1.0f)) : 0.f;
    }
#pragma unroll
    for (int ct = 0; ct < 8; ++ct) {
      f32x4 acc = {0.f, 0.f, 0.f, 0.f};
      const int brow = ct * 16 + l15;
#pragma unroll
      for (int kt = 0; kt < 2; ++kt) {
        const short8 b = *(const short8*)&Wl[brow * FIN + (((kt * 4 + quad) ^ (l15 & 7)) << 3)];
        acc = __builtin_amdgcn_mfma_f32_16x16x32_bf16(a[kt], b, acc, 0, 0, 0);
      }
      const int n = ct * 16 + l15;
#pragma unroll
      for (int r = 0; r < 4; ++r)
        if (rows[r] < NSTRIP) Y[(size_t)(base + rows[r]) * HID + n] = f2bf(acc[r] * sc[r]);
    }
  }
}

// ---------------------------------------------------------------------------
// Layer-2 GEMM (MFMA bf16), fused GraphNorm apply, bf16 in/out, XCD-swizzled.
// ---------------------------------------------------------------------------
__global__ __launch_bounds__(256) void gemm_norm_k(const u16* __restrict__ Xb,
                                                   const u16* __restrict__ Wt,
                                                   const float* __restrict__ An,
                                                   const float* __restrict__ Bn,
                                                   const int* __restrict__ cout_,
                                                   u16* __restrict__ Y) {
  __shared__ u16 Xl[64 * HID];
  __shared__ u16 Wl[HID * HID];
  const int tid = threadIdx.x;
  const int wave = tid >> 6, lane = tid & 63, l15 = lane & 15, quad = lane >> 4;
  int g, part;
  if (!swz(blockIdx.x, 4, g, part)) return;
  const int base = g * NPG + part * NSTRIP;

  for (int i = tid; i < HID * (HID / 8); i += 256) {  // 2048 chunks
    const int n = i >> 4, c = i & 15;
    const short8 w = *(const short8*)(Wt + n * HID + c * 8);
    *(short8*)&Wl[n * HID + ((c ^ (n & 15)) << 3)] = w;
  }
  for (int pass = 0; pass < 4; ++pass) {
    __syncthreads();
    for (int i = tid; i < 64 * 16; i += 256) {  // 4 iters, 8 elems each
      const int r = i >> 4;
      const int c8 = i & 15;
      const int rowi = pass * 64 + r;
      short8 o = {0, 0, 0, 0, 0, 0, 0, 0};
      if (rowi < NSTRIP) {
        const int node = base + rowi;
        const short8 xs = *(const short8*)(Xb + (size_t)node * HID + c8 * 8);
        const float4 Aa = *(const float4*)(An + (size_t)g * HID + c8 * 8);
        const float4 Ab = *(const float4*)(An + (size_t)g * HID + c8 * 8 + 4);
        const float4 Ba = *(const float4*)(Bn + (size_t)g * HID + c8 * 8);
        const float4 Bb = *(const float4*)(Bn + (size_t)g * HID + c8 * 8 + 4);
        const float Av[8] = {Aa.x, Aa.y, Aa.z, Aa.w, Ab.x, Ab.y, Ab.z, Ab.w};
        const float Bv[8] = {Ba.x, Ba.y, Ba.z, Ba.w, Bb.x, Bb.y, Bb.z, Bb.w};
#pragma unroll
        for (int j = 0; j < 8; ++j)
          o[j] = (short)f2bf(leaky(fmaf(Av[j], bf2f((u16)xs[j]), Bv[j])));
      }
      *(short8*)&Xl[r * HID + ((c8 ^ (r & 15)) << 3)] = o;
    }
    __syncthreads();
    short8 a[4];
    const int arow = wave * 16 + l15;
#pragma unroll
    for (int kt = 0; kt < 4; ++kt)
      a[kt] = *(const short8*)&Xl[arow * HID + (((kt * 4 + quad) ^ l15) << 3)];
    float sc[4];
    int rows[4];
#pragma unroll
    for (int r = 0; r < 4; ++r) {
      rows[r] = pass * 64 + wave * 16 + quad * 4 + r;
      sc[r] = (rows[r] < NSTRIP) ? rsqrtf(fmaxf((float)cout_[base + rows[r]], 1.0f)) : 0.f;
    }
#pragma unroll
    for (int ct = 0; ct < 8; ++ct) {
      f32x4 acc = {0.f, 0.f, 0.f, 0.f};
      const int brow = ct * 16 + l15;
#pragma unroll
      for (int kt = 0; kt < 4; ++kt) {
        const short8 b = *(const short8*)&Wl[brow * HID + (((kt * 4 + quad) ^ l15) << 3)];
        acc = __builtin_amdgcn_mfma_f32_16x16x32_bf16(a[kt], b, acc, 0, 0, 0);
      }
      const int n = ct * 16 + l15;
#pragma unroll
      for (int r = 0; r < 4; ++r)
        if (rows[r] < NSTRIP) Y[(size_t)(base + rows[r]) * HID + n] = f2bf(acc[r] * sc[r]);
    }
  }
}

// ---------------------------------------------------------------------------
// Readout phi+pool (MFMA bf16), fused norm apply, bf16 input, XCD-swizzled.
// ---------------------------------------------------------------------------
__global__ __launch_bounds__(256) void phi_pool_k(const u16* __restrict__ Xb,
                                                  const float* __restrict__ An,
                                                  const float* __restrict__ Bn,
                                                  const u16* __restrict__ Wt,
                                                  const float* __restrict__ b1,
                                                  float* __restrict__ phi_sum,
                                                  float* __restrict__ h_sum) {
  __shared__ u16 Xl[64 * HID];          // 16 KB
  __shared__ u16 Wl[HID * HID];         // 32 KB
  __shared__ float red[16][HID];        //  8 KB
  __shared__ float hred[16][HID];       //  8 KB  (64 KB total)
  const int tid = threadIdx.x;
  const int wave = tid >> 6, lane = tid & 63, l15 = lane & 15, quad = lane >> 4;
  int g, part;
  if (!swz(blockIdx.x, 4, g, part)) return;
  const int base = g * NPG + part * NSTRIP;

  for (int i = tid; i < HID * (HID / 8); i += 256) {
    const int n = i >> 4, c = i & 15;
    const short8 w = *(const short8*)(Wt + n * HID + c * 8);
    *(short8*)&Wl[n * HID + ((c ^ (n & 15)) << 3)] = w;
  }
  float bcol[8];
#pragma unroll
  for (int ct = 0; ct < 8; ++ct) bcol[ct] = b1[ct * 16 + l15];

  float pooled[8] = {0.f, 0.f, 0.f, 0.f, 0.f, 0.f, 0.f, 0.f};
  float hp[8] = {0.f, 0.f, 0.f, 0.f, 0.f, 0.f, 0.f, 0.f};

  for (int pass = 0; pass < 4; ++pass) {
    __syncthreads();
    for (int i = tid; i < 64 * 16; i += 256) {
      const int r = i >> 4;
      const int c8 = i & 15;   // == tid&15 (stride 256)
      const int rowi = pass * 64 + r;
      short8 o = {0, 0, 0, 0, 0, 0, 0, 0};
      if (rowi < NSTRIP) {
        const int node = base + rowi;
        const short8 xs = *(const short8*)(Xb + (size_t)node * HID + c8 * 8);
        const float4 Aa = *(const float4*)(An + (size_t)g * HID + c8 * 8);
        const float4 Ab = *(const float4*)(An + (size_t)g * HID + c8 * 8 + 4);
        const float4 Ba = *(const float4*)(Bn + (size_t)g * HID + c8 * 8);
        const float4 Bb = *(const float4*)(Bn + (size_t)g * HID + c8 * 8 + 4);
        const float Av[8] = {Aa.x, Aa.y, Aa.z, Aa.w, Ab.x, Ab.y, Ab.z, Ab.w};
        const float Bv[8] = {Ba.x, Ba.y, Ba.z, Ba.w, Bb.x, Bb.y, Bb.z, Bb.w};
#pragma unroll
        for (int j = 0; j < 8; ++j) {
          const float xn = leaky(fmaf(Av[j], bf2f((u16)xs[j]), Bv[j]));
          hp[j] += xn;
          o[j] = (short)f2bf(xn);
        }
      }
      *(short8*)&Xl[r * HID + ((c8 ^ (r & 15)) << 3)] = o;
    }
    __syncthreads();
    short8 a[4];
    const int arow = wave * 16 + l15;
#pragma unroll
    for (int kt = 0; kt < 4; ++kt)
      a[kt] = *(const short8*)&Xl[arow * HID + (((kt * 4 + quad) ^ l15) << 3)];
#pragma unroll
    for (int ct = 0; ct < 8; ++ct) {
      f32x4 acc = {0.f, 0.f, 0.f, 0.f};
      const int brow = ct * 16 + l15;
#pragma unroll
      for (int kt = 0; kt < 4; ++kt) {
        const short8 b = *(const short8*)&Wl[brow * HID + (((kt * 4 + quad) ^ l15) << 3)];
        acc = __builtin_amdgcn_mfma_f32_16x16x32_bf16(a[kt], b, acc, 0, 0, 0);
      }
#pragma unroll
      for (int r = 0; r < 4; ++r) {
        const int rowi = pass * 64 + wave * 16 + quad * 4 + r;
        if (rowi < NSTRIP) pooled[ct] += leaky(acc[r] + bcol[ct]);
      }
    }
  }
  const int qi = wave * 4 + quad;
#pragma unroll
  for (int ct = 0; ct < 8; ++ct) red[qi][ct * 16 + l15] = pooled[ct];
#pragma unroll
  for (int j = 0; j < 8; ++j) hred[tid >> 4][(tid & 15) * 8 + j] = hp[j];
  __syncthreads();
  if (tid < HID) {
    float s = 0.f;
#pragma unroll
    for (int q = 0; q < 16; ++q) s += red[q][tid];
    unsafeAtomicAdd(&phi_sum[g * HID + tid], s);
  } else {
    const int t = tid - HID;
    float s = 0.f;
#pragma unroll
    for (int rr = 0; rr < 16; ++rr) s += hred[rr][t];
    unsafeAtomicAdd(&h_sum[g * HID + t], s);
  }
}

// ---------------------------------------------------------------------------
// Atomic-free aggregation (bf16 in/out) from int2 CSR + in_isqrt + fused
// per-graph stats. Coalesced int2 prefetch + shuffle broadcast, 4 edges in
// flight, one bf16-pair dword per lane per edge.
// ---------------------------------------------------------------------------
__global__ __launch_bounds__(256) void gather_k(const u16* __restrict__ H,
                                                const int2* __restrict__ csr,
                                                const int* __restrict__ offs,
                                                const int* __restrict__ cin_,
                                                u16* __restrict__ AGG,
                                                float* __restrict__ sx,
                                                float* __restrict__ sq) {
  __shared__ float redx[4][HID];
  __shared__ float redq[4][HID];
  const int wave = threadIdx.x >> 6;
  const int lane = threadIdx.x & 63;
  int g, part;
  if (!swz(blockIdx.x, 25, g, part)) return;
  const int base = g * NPG + part * GSN;

  float sxa = 0.f, sxb = 0.f, sqa = 0.f, sqb = 0.f;
  for (int n = base + wave; n < base + GSN; n += 4) {
    const int off = offs[n];
    const int cnt = cin_[n];
    const float isq = rsqrtf(fmaxf((float)cnt, 1.0f));
    float ax = 0.f, ay = 0.f, bx = 0.f, by = 0.f;
    int i = 0;
    while (i < cnt) {
      const int take = min(cnt - i, 64);
      int2 rec = make_int2(0, 0);
      if (lane < take) rec = csr[off + i + lane];
      int t = 0;
      for (; t + 4 <= take; t += 4) {
        const int s0 = __shfl(rec.x, t), s1 = __shfl(rec.x, t + 1);
        const int s2 = __shfl(rec.x, t + 2), s3 = __shfl(rec.x, t + 3);
        const float w0 = __int_as_float(__shfl(rec.y, t));
        const float w1 = __int_as_float(__shfl(rec.y, t + 1));
        const float w2 = __int_as_float(__shfl(rec.y, t + 2));
        const float w3 = __int_as_float(__shfl(rec.y, t + 3));
        const unsigned u0 = *(const unsigned*)(H + (size_t)s0 * HID + lane * 2);
        const unsigned u1 = *(const unsigned*)(H + (size_t)s1 * HID + lane * 2);
        const unsigned u2 = *(const unsigned*)(H + (size_t)s2 * HID + lane * 2);
        const unsigned u3 = *(const unsigned*)(H + (size_t)s3 * HID + lane * 2);
        ax = fmaf(w0, __uint_as_float(u0 << 16), ax);
        ay = fmaf(w0, __uint_as_float(u0 & 0xffff0000u), ay);
        bx = fmaf(w1, __uint_as_float(u1 << 16), bx);
        by = fmaf(w1, __uint_as_float(u1 & 0xffff0000u), by);
        ax = fmaf(w2, __uint_as_float(u2 << 16), ax);
        ay = fmaf(w2, __uint_as_float(u2 & 0xffff0000u), ay);
        bx = fmaf(w3, __uint_as_float(u3 << 16), bx);
        by = fmaf(w3, __uint_as_float(u3 & 0xffff0000u), by);
      }
      for (; t < take; ++t) {
        const int s0 = __shfl(rec.x, t);
        const float w0 = __int_as_float(__shfl(rec.y, t));
        const unsigned u0 = *(const unsigned*)(H + (size_t)s0 * HID + lane * 2);
        ax = fmaf(w0, __uint_as_float(u0 << 16), ax);
        ay = fmaf(w0, __uint_as_float(u0 & 0xffff0000u), ay);
      }
      i += take;
    }
    const float rx = (ax + bx) * isq;
    const float ry = (ay + by) * isq;
    const unsigned pk = (unsigned)f2bf(rx) | ((unsigned)f2bf(ry) << 16);
    *(unsigned*)(AGG + (size_t)n * HID + lane * 2) = pk;
    sxa += rx; sxb += ry;
    sqa += rx * rx; sqb += ry * ry;
  }
  redx[wave][lane * 2] = sxa; redx[wave][lane * 2 + 1] = sxb;
  redq[wave][lane * 2] = sqa; redq[wave][lane * 2 + 1] = sqb;
  __syncthreads();
  const int tid = threadIdx.x;
  if (tid < HID) {
    unsafeAtomicAdd(&sx[g * HID + tid],
                    redx[0][tid] + redx[1][tid] + redx[2][tid] + redx[3][tid]);
  } else {
    const int t = tid - HID;
    unsafeAtomicAdd(&sq[g * HID + t],
                    redq[0][t] + redq[1][t] + redq[2][t] + redq[3][t]);
  }
}

// ---------------------------------------------------------------------------
// Fold stats into affine: normalized = A*x + B per (graph, feat).
// ---------------------------------------------------------------------------
__global__ __launch_bounds__(HID) void stats_k(const float* __restrict__ sx,
                                               const float* __restrict__ sq,
                                               const float* __restrict__ alpha,
                                               const float* __restrict__ gamma,
                                               const float* __restrict__ beta,
                                               float* __restrict__ An,
                                               float* __restrict__ Bn) {
  const int g = (blockIdx.x & 7) + 8 * (blockIdx.x >> 3);
  if (g >= NG) return;
  const int j = threadIdx.x;
  const float mean = sx[g * HID + j] * (1.0f / NPG);
  const float ex2 = sq[g * HID + j] * (1.0f / NPG);
  const float am = alpha[j] * mean;
  float var = ex2 - 2.0f * am * mean + am * am;
  var = fmaxf(var, 0.0f);
  const float rstd = rsqrtf(var + EPSV);
  const float A = gamma[j] * rstd;
  An[g * HID + j] = A;
  Bn[g * HID + j] = beta[j] - A * am;
}

// ---------------------------------------------------------------------------
// Readout part 2.
// ---------------------------------------------------------------------------
__global__ __launch_bounds__(64) void finalize_k(const float* __restrict__ phi_sum,
                                                 const float* __restrict__ h_sum,
                                                 const float* __restrict__ w2,
                                                 const float* __restrict__ b2,
                                                 float* __restrict__ out,
                                                 int roff, int moff) {
  const int g = blockIdx.x;
  const int j = threadIdx.x;  // 0..63
  float acc = b2[j];
#pragma unroll 8
  for (int k = 0; k < HID; ++k)
    acc += (phi_sum[g * HID + k] * (1.0f / NPG)) * w2[k * RD + j];
  const float r = leaky(acc);
  out[g * 384 + roff + j] = leaky(r);
  out[g * 384 + moff + j] = leaky(h_sum[g * HID + j] * (1.0f / NPG));
  out[g * 384 + moff + 64 + j] = leaky(h_sum[g * HID + 64 + j] * (1.0f / NPG));
}

// ---------------------------------------------------------------------------
extern "C" void kernel_launch(void* const* d_in, const int* in_sizes, int n_in,
                              void* d_out, int out_size, void* d_ws, size_t ws_size,
                              hipStream_t stream) {
  const float* node_feats = (const float*)d_in[0];
  const float* ew   = (const float*)d_in[1];
  const float* W1   = (const float*)d_in[2];
  const float* W2   = (const float*)d_in[3];
  const float* g1a  = (const float*)d_in[4];
  const float* g1g  = (const float*)d_in[5];
  const float* g1b  = (const float*)d_in[6];
  const float* g2a  = (const float*)d_in[7];
  const float* g2g  = (const float*)d_in[8];
  const float* g2b  = (const float*)d_in[9];
  const float* r1w1 = (const float*)d_in[10];
  const float* r1b1 = (const float*)d_in[11];
  const float* r1w2 = (const float*)d_in[12];
  const float* r1b2 = (const float*)d_in[13];
  const float* r2w1 = (const float*)d_in[14];
  const float* r2b1 = (const float*)d_in[15];
  const float* r2w2 = (const float*)d_in[16];
  const float* r2b2 = (const float*)d_in[17];
  const int* src = (const int*)d_in[18];
  const int* dst = (const int*)d_in[19];
  float* out = (float*)d_out;

  // workspace layout (zeroed region first: phi/h pooled sums + sx/sq)
  char* wsb = (char*)d_ws;
  float* ps1     = (float*)wsb;                       // NG*HID x8, zeroed
  float* hs1     = ps1 + NG * HID;
  float* ps2     = hs1 + NG * HID;
  float* hs2     = ps2 + NG * HID;
  float* sx1     = hs2 + NG * HID;
  float* sq1     = sx1 + NG * HID;
  float* sx2     = sq1 + NG * HID;
  float* sq2     = sx2 + NG * HID;
  int*   cin     = (int*)(sq2 + NG * HID);            // NN (direct store)
  int*   cout_   = cin + NN;                          // NN (direct store)
  int*   offs    = cout_ + NN;                        // NN (direct store)
  int2*  csr     = (int2*)(offs + NN);                // NE int2 (12.8 MB)
  float* A1      = (float*)(csr + NE);                // NG*HID x4
  float* B1      = A1 + NG * HID;
  float* A2      = B1 + NG * HID;
  float* B2      = A2 + NG * HID;
  u16*   Wt1     = (u16*)(B2 + NG * HID);             // 128*64
  u16*   Wt2     = Wt1 + HID * FIN;                   // 128*128 x3
  u16*   Rt1     = Wt2 + HID * HID;
  u16*   Rt2     = Rt1 + HID * HID;
  u16*   bufA    = Rt2 + HID * HID;                   // NN*HID bf16
  u16*   bufB    = bufA + (size_t)NN * HID;           // NN*HID bf16

  hipMemsetAsync(d_ws, 0, (size_t)(8 * NG * HID) * sizeof(float), stream);

  // weight transpose + per-graph CSR build (per call)
  wt_k<<<(FIN * HID + 3 * HID * HID) / 256, 256, 0, stream>>>(
      W1, W2, r1w1, r2w1, Wt1, Wt2, Rt1, Rt2);
  build_k<<<8 * 13, 1024, 0, stream>>>(src, dst, ew, cin, cout_, offs, csr);

  const int gemm_grid = 8 * 4 * 13;     // XCD-swizzled, 4 strips/graph
  const int gather_grid = 8 * 25 * 13;  // XCD-swizzled, 25 strips/graph
  const int stats_grid = 8 * 13;

  // ---- layer 1 ----
  gemm1_k<<<gemm_grid, 256, 0, stream>>>(node_feats, Wt1, cout_, bufA);
  gather_k<<<gather_grid, 256, 0, stream>>>(bufA, csr, offs, cin, bufB, sx1, sq1);
  stats_k<<<stats_grid, HID, 0, stream>>>(sx1, sq1, g1a, g1g, g1b, A1, B1);
  phi_pool_k<<<gemm_grid, 256, 0, stream>>>(bufB, A1, B1, Rt1, r1b1, ps1, hs1);
  finalize_k<<<NG, 64, 0, stream>>>(ps1, hs1, r1w2, r1b2, out, 0, 64);

  // ---- layer 2 ----
  gemm_norm_k<<<gemm_grid, 256, 0, stream>>>(bufB, Wt2, A1, B1, cout_, bufA);
  gather_k<<<gather_grid, 256, 0, stream>>>(bufA, csr, offs, cin, bufB, sx2, sq2);
  stats_k<<<stats_grid, HID, 0, stream>>>(sx2, sq2, g2a, g2g, g2b, A2, B2);
  phi_pool_k<<<gemm_grid, 256, 0, stream>>>(bufB, A2, B2, Rt2, r2b1, ps2, hs2);
  finalize_k<<<NG, 64, 0, stream>>>(ps2, hs2, r2w2, r2b2, out, 192, 256);
}